// Round 2
// baseline (464.827 us; speedup 1.0000x reference)
//
#include <hip/hip_runtime.h>

typedef unsigned short u16;
typedef unsigned int u32;
typedef __attribute__((ext_vector_type(8))) short short8;
typedef __attribute__((ext_vector_type(4))) float floatx4;

#define GLOAD_LDS16(gp, lp)                                                              \
  __builtin_amdgcn_global_load_lds((const __attribute__((address_space(1))) void*)(gp),  \
                                   (__attribute__((address_space(3))) void*)(lp), 16, 0, 0)

__device__ __forceinline__ u16 f2bf(float f) {
  u32 u = __float_as_uint(f);
  u += 0x7fffu + ((u >> 16) & 1u);   // round-to-nearest-even
  return (u16)(u >> 16);
}

// ---------------- transpose + fp32->bf16 convert:  W[e][K][N] -> WT[e][N][K] ----------
__global__ __launch_bounds__(256) void wtrans_kernel(const float* __restrict__ W,
                                                     u16* __restrict__ WT,
                                                     int K, int N) {
  __shared__ float tile[64][65];
  const int t = threadIdx.x;
  const int e = blockIdx.z;
  const int n0 = blockIdx.x * 64;
  const int k0 = blockIdx.y * 64;
  const float* Wp = W + ((size_t)e * K + k0) * N + n0;
  const int r = t >> 4;          // 0..15
  const int c = (t & 15) << 2;   // 0..60
#pragma unroll
  for (int p = 0; p < 4; p++) {
    const int row = r + p * 16;
    const float4 v = *(const float4*)(Wp + (size_t)row * N + c);
    tile[row][c + 0] = v.x; tile[row][c + 1] = v.y;
    tile[row][c + 2] = v.z; tile[row][c + 3] = v.w;
  }
  __syncthreads();
  u16* WTp = WT + ((size_t)e * N + n0) * K + k0;
#pragma unroll
  for (int p = 0; p < 4; p++) {
    const int row = r + p * 16;  // n index within tile
    u32 lo = (u32)f2bf(tile[c + 0][row]) | ((u32)f2bf(tile[c + 1][row]) << 16);
    u32 hi = (u32)f2bf(tile[c + 2][row]) | ((u32)f2bf(tile[c + 3][row]) << 16);
    *(uint2*)(WTp + (size_t)row * K + c) = make_uint2(lo, hi);
  }
}

// ---------------- Wg[m][512][18] fp32 -> WgT[m][18][512] fp32 -------------------------
__global__ __launch_bounds__(256) void wgtrans_kernel(const float* __restrict__ Wg,
                                                      float* __restrict__ WgT, int total) {
  int idx = blockIdx.x * 256 + threadIdx.x;
  if (idx >= total) return;
  int d = idx & 511;
  int r = idx >> 9;
  int e = r % 18;
  int m = r / 18;
  WgT[idx] = Wg[((size_t)(m * 512 + d)) * 18 + e];
}

// ---------------- elementwise fp32 -> bf16 --------------------------------------------
__global__ __launch_bounds__(256) void cvtbf_kernel(const float* __restrict__ src,
                                                    u16* __restrict__ dst, int n4) {
  int i = blockIdx.x * 256 + threadIdx.x;
  if (i >= n4) return;
  float4 v = ((const float4*)src)[i];
  u32 lo = (u32)f2bf(v.x) | ((u32)f2bf(v.y) << 16);
  u32 hi = (u32)f2bf(v.z) | ((u32)f2bf(v.w) << 16);
  ((uint2*)dst)[i] = make_uint2(lo, hi);
}

// ---------------- MFMA GEMM: C[r][n] (+bias[n]) = A[r][:] * BT[n][:]^T ----------------
// A bf16 rows (batch), BT bf16 [e][N][K]; 128x128 tile, BK=64, 4 waves 2x2, 4x4 mfma/wave
template <bool RELU_BF16_OUT>
__global__ __launch_bounds__(256, 3) void gemm_kernel(
    const u16* __restrict__ A, const u16* __restrict__ BT,
    const float* __restrict__ bias, void* __restrict__ Cout,
    int lda, int a_shift, int a_mul, int ldc, int c_mul, int N, int K) {
  __shared__ __align__(16) u16 As[128 * 64];
  __shared__ __align__(16) u16 Bs[128 * 64];

  const int tid = threadIdx.x;
  const int lane = tid & 63;
  const int wave = tid >> 6;
  const int e = blockIdx.y;
  const int mt = blockIdx.x & 7;   // M = 1024 always -> 8 row tiles
  const int nt = blockIdx.x >> 3;
  const int m0 = mt << 7, n0 = nt << 7;

  const u16* Aexp = A + (size_t)((e >> a_shift) * a_mul);
  const u16* Bexp = BT + (size_t)e * (size_t)N * (size_t)K;

  // staging: chunk c (of 16) = 1KB = 8 rows; lane l -> row c*8 + l/8, swizzled col group
  const int colsw = (((lane & 7) ^ ((lane >> 3) & 7)) << 3);
  const u16* aptr[4];
  const u16* bptr[4];
  u16* lA[4];
  u16* lB[4];
#pragma unroll
  for (int i = 0; i < 4; i++) {
    const int cch = wave * 4 + i;
    const int row = cch * 8 + (lane >> 3);
    aptr[i] = Aexp + (size_t)(m0 + row) * lda + colsw;
    bptr[i] = Bexp + (size_t)(n0 + row) * K + colsw;
    lA[i] = As + cch * 512;
    lB[i] = Bs + cch * 512;
  }

  floatx4 acc[4][4];
#pragma unroll
  for (int i = 0; i < 4; i++)
#pragma unroll
    for (int j = 0; j < 4; j++) acc[i][j] = (floatx4){0.f, 0.f, 0.f, 0.f};

  const int wm = (wave & 1) << 6;
  const int wn = (wave >> 1) << 6;
  const int r15 = lane & 15;
  const int quad = lane >> 4;

  // fragment LDS offsets (elements), substep s=1 is ^32 (xor-swizzle is linear)
  int aoff[4], boff[4];
#pragma unroll
  for (int i = 0; i < 4; i++) {
    const int ra = wm + i * 16 + r15;
    aoff[i] = ra * 64 + ((quad ^ (ra & 7)) << 3);
    const int rb = wn + i * 16 + r15;
    boff[i] = rb * 64 + ((quad ^ (rb & 7)) << 3);
  }

  for (int k0 = 0; k0 < K; k0 += 64) {
    __syncthreads();
#pragma unroll
    for (int i = 0; i < 4; i++) GLOAD_LDS16(aptr[i] + k0, lA[i]);
#pragma unroll
    for (int i = 0; i < 4; i++) GLOAD_LDS16(bptr[i] + k0, lB[i]);
    __syncthreads();
#pragma unroll
    for (int s = 0; s < 2; s++) {
      short8 af[4], bfr[4];
#pragma unroll
      for (int i = 0; i < 4; i++) af[i] = *(const short8*)(As + (aoff[i] ^ (s << 5)));
#pragma unroll
      for (int j = 0; j < 4; j++) bfr[j] = *(const short8*)(Bs + (boff[j] ^ (s << 5)));
#pragma unroll
      for (int i = 0; i < 4; i++)
#pragma unroll
        for (int j = 0; j < 4; j++)
          acc[i][j] = __builtin_amdgcn_mfma_f32_16x16x32_bf16(af[i], bfr[j], acc[i][j], 0, 0, 0);
    }
  }

  const int ccol0 = n0 + wn + r15;
  const int crow0 = m0 + wm + quad * 4;
  float bv[4];
#pragma unroll
  for (int j = 0; j < 4; j++) bv[j] = bias[e * N + ccol0 + j * 16];

  if constexpr (RELU_BF16_OUT) {
    u16* Co = (u16*)Cout + (size_t)e * c_mul;
#pragma unroll
    for (int i = 0; i < 4; i++)
#pragma unroll
      for (int r = 0; r < 4; r++) {
        const size_t rowoff = (size_t)(crow0 + i * 16 + r) * ldc;
#pragma unroll
        for (int j = 0; j < 4; j++) {
          float v = acc[i][j][r] + bv[j];
          v = v > 0.f ? v : 0.f;
          Co[rowoff + ccol0 + j * 16] = f2bf(v);
        }
      }
  } else {
    float* Co = (float*)Cout + (size_t)e * c_mul;
#pragma unroll
    for (int i = 0; i < 4; i++)
#pragma unroll
      for (int r = 0; r < 4; r++) {
        const size_t rowoff = (size_t)(crow0 + i * 16 + r) * ldc;
#pragma unroll
        for (int j = 0; j < 4; j++) Co[rowoff + ccol0 + j * 16] = acc[i][j][r] + bv[j];
      }
  }
}

// ---------------- fused gating(softmax+add) + combine ---------------------------------
// one block per batch b; x fp32 [B][9][512]; eo fp32 [B][18][512]; WgT fp32 [M][18][512]
template <int M, int LAYER, bool WBF>
__global__ __launch_bounds__(256) void combine_kernel(
    const float* __restrict__ x, const float* __restrict__ eo,
    const float* __restrict__ WgT, const float* __restrict__ bg,
    const float* __restrict__ sew_task, const float* __restrict__ sew_shared,
    float* __restrict__ out, u16* __restrict__ outbf) {
  __shared__ float xs[M * 512];
  __shared__ float eos[18 * 512];
  __shared__ float lg[M * 18];
  __shared__ float wsm[M * 18];
  const int t = threadIdx.x;
  const int b = blockIdx.x;
  const float* xb = x + (size_t)b * 4608;     // x row-stride is always 9*512
  const float* eob = eo + (size_t)b * 9216;
  for (int i = t; i < M * 128; i += 256) ((float4*)xs)[i] = ((const float4*)xb)[i];
  for (int i = t; i < 18 * 128; i += 256) ((float4*)eos)[i] = ((const float4*)eob)[i];
  __syncthreads();
  if (t < M * 18) {
    const int m = t / 18;
    const float* wrow = WgT + (size_t)t * 512;
    const float* xr = xs + m * 512;
    float ax = 0.f, ay = 0.f, az = 0.f, aw = 0.f;
#pragma unroll 4
    for (int d4 = 0; d4 < 128; d4++) {
      const float4 wv = ((const float4*)wrow)[d4];
      const float4 xv = ((const float4*)xr)[d4];
      ax += wv.x * xv.x; ay += wv.y * xv.y; az += wv.z * xv.z; aw += wv.w * xv.w;
    }
    lg[t] = bg[t] + ax + ay + az + aw;
  }
  __syncthreads();
  if (t < M * 18) {
    const int m = t / 18, ei = t % 18;
    float mx = -3.4e38f;
    for (int e = 0; e < 18; e++) mx = fmaxf(mx, lg[m * 18 + e]);
    float s = 0.f;
    for (int e = 0; e < 18; e++) s += expf(lg[m * 18 + e] - mx);
    float w = expf(lg[t] - mx) / s;
    if ((ei >> 1) == m) {
      if (m < 8) w += sew_task[m * 4 + 2 * LAYER + (ei & 1)];
      else       w += sew_shared[ei & 1];    // only layer 0 has the shared module row
    }
    wsm[t] = w;
  }
  __syncthreads();
  float* ob = out + (size_t)b * (M * 512);
  for (int idx = t; idx < M * 128; idx += 256) {
    const int m = idx >> 7;
    const int d4 = idx & 127;
    const float* wr = wsm + m * 18;
    float ox = 0.f, oy = 0.f, oz = 0.f, ow = 0.f;
#pragma unroll
    for (int e = 0; e < 18; e++) {
      const float w = wr[e];
      const float4 v = ((const float4*)(eos + e * 512))[d4];
      ox += w * v.x; oy += w * v.y; oz += w * v.z; ow += w * v.w;
    }
    float4 o = {ox, oy, oz, ow};
    ((float4*)ob)[idx] = o;
    if constexpr (WBF) {
      u16* obf = outbf + (size_t)b * (M * 512);
      u32 lo = (u32)f2bf(o.x) | ((u32)f2bf(o.y) << 16);
      u32 hi = (u32)f2bf(o.z) | ((u32)f2bf(o.w) << 16);
      ((uint2*)obf)[idx] = make_uint2(lo, hi);
    }
  }
}

extern "C" void kernel_launch(void* const* d_in, const int* in_sizes, int n_in,
                              void* d_out, int out_size, void* d_ws, size_t ws_size,
                              hipStream_t stream) {
  const float* x0   = (const float*)d_in[0];
  const float* W1_0 = (const float*)d_in[1];
  const float* b1_0 = (const float*)d_in[2];
  const float* W2_0 = (const float*)d_in[3];
  const float* b2_0 = (const float*)d_in[4];
  const float* Wg_0 = (const float*)d_in[5];
  const float* bg_0 = (const float*)d_in[6];
  const float* W1_1 = (const float*)d_in[7];
  const float* b1_1 = (const float*)d_in[8];
  const float* W2_1 = (const float*)d_in[9];
  const float* b2_1 = (const float*)d_in[10];
  const float* Wg_1 = (const float*)d_in[11];
  const float* bg_1 = (const float*)d_in[12];
  const float* sewt = (const float*)d_in[13];
  const float* sews = (const float*)d_in[14];
  float* out = (float*)d_out;

  char* p = (char*)d_ws;
  auto take = [&](size_t n) { char* r = p; p += (n + 255) & ~(size_t)255; return r; };
  u16*   x0bf = (u16*)take(4718592ull * 2);     // [B][9][512] bf16
  u16*   W1T0 = (u16*)take(9437184ull * 2);     // [18][1024][512] bf16
  u16*   W2T0 = (u16*)take(9437184ull * 2);     // [18][512][1024] bf16
  u16*   W1T1 = (u16*)take(9437184ull * 2);
  u16*   W2T1 = (u16*)take(9437184ull * 2);
  float* WgT0 = (float*)take(82944ull * 4);     // [9][18][512] fp32
  float* WgT1 = (float*)take(73728ull * 4);     // [8][18][512] fp32
  u16*   hbf  = (u16*)take(18874368ull * 2);    // [B][18][1024] bf16
  float* eo   = (float*)take(9437184ull * 4);   // [B][18][512] fp32
  float* x1   = (float*)take(4718592ull * 4);   // [B][9][512] fp32
  u16*   x1bf = (u16*)take(4718592ull * 2);     // [B][9][512] bf16

  dim3 blk(256);
  // weight transposes + converts
  wtrans_kernel<<<dim3(16, 8, 18), blk, 0, stream>>>(W1_0, W1T0, 512, 1024);
  wtrans_kernel<<<dim3(8, 16, 18), blk, 0, stream>>>(W2_0, W2T0, 1024, 512);
  wtrans_kernel<<<dim3(16, 8, 18), blk, 0, stream>>>(W1_1, W1T1, 512, 1024);
  wtrans_kernel<<<dim3(8, 16, 18), blk, 0, stream>>>(W2_1, W2T1, 1024, 512);
  wgtrans_kernel<<<dim3(324), blk, 0, stream>>>(Wg_0, WgT0, 82944);
  wgtrans_kernel<<<dim3(288), blk, 0, stream>>>(Wg_1, WgT1, 73728);
  cvtbf_kernel<<<dim3(4608), blk, 0, stream>>>(x0, x0bf, 1179648);

  // layer 0: h = relu(x W1 + b1) ; eo = h W2 + b2 ; combine(+gating)
  gemm_kernel<true><<<dim3(64, 18), blk, 0, stream>>>(
      x0bf, W1T0, b1_0, (void*)hbf, 4608, 1, 512, 18432, 1024, 1024, 512);
  gemm_kernel<false><<<dim3(32, 18), blk, 0, stream>>>(
      hbf, W2T0, b2_0, (void*)eo, 18432, 0, 1024, 9216, 512, 512, 1024);
  combine_kernel<9, 0, true><<<dim3(1024), blk, 0, stream>>>(
      x0, eo, WgT0, bg_0, sewt, sews, x1, x1bf);

  // layer 1
  gemm_kernel<true><<<dim3(64, 18), blk, 0, stream>>>(
      x1bf, W1T1, b1_1, (void*)hbf, 4608, 1, 512, 18432, 1024, 1024, 512);
  gemm_kernel<false><<<dim3(32, 18), blk, 0, stream>>>(
      hbf, W2T1, b2_1, (void*)eo, 18432, 0, 1024, 9216, 512, 512, 1024);
  combine_kernel<8, 1, false><<<dim3(1024), blk, 0, stream>>>(
      x1, eo, WgT1, bg_1, sewt, sews, out, nullptr);
}

// Round 4
// 406.859 us; speedup vs baseline: 1.1425x; 1.1425x over previous
//
#include <hip/hip_runtime.h>

typedef unsigned short u16;
typedef unsigned int u32;
typedef __attribute__((ext_vector_type(8))) short short8;
typedef __attribute__((ext_vector_type(4))) float floatx4;

#define GLOAD_LDS16(gp, lp)                                                              \
  __builtin_amdgcn_global_load_lds((const __attribute__((address_space(1))) void*)(gp),  \
                                   (__attribute__((address_space(3))) void*)(lp), 16, 0, 0)

__device__ __forceinline__ u16 f2bf(float f) {
  u32 u = __float_as_uint(f);
  u += 0x7fffu + ((u >> 16) & 1u);   // round-to-nearest-even
  return (u16)(u >> 16);
}

__device__ __forceinline__ void bf8_to_f(const u16* p, float* o) {
  const uint4 v = *(const uint4*)p;
  const u32 a[4] = {v.x, v.y, v.z, v.w};
#pragma unroll
  for (int i = 0; i < 4; i++) {
    o[2 * i]     = __uint_as_float(a[i] << 16);
    o[2 * i + 1] = __uint_as_float(a[i] & 0xffff0000u);
  }
}

// ---------------- transpose + fp32->bf16 convert:  W[e][K][N] -> WT[e][N][K] ----------
__global__ __launch_bounds__(256) void wtrans_kernel(const float* __restrict__ W,
                                                     u16* __restrict__ WT,
                                                     int K, int N) {
  __shared__ float tile[64][65];
  const int t = threadIdx.x;
  const int e = blockIdx.z;
  const int n0 = blockIdx.x * 64;
  const int k0 = blockIdx.y * 64;
  const float* Wp = W + ((size_t)e * K + k0) * N + n0;
  const int r = t >> 4;          // 0..15
  const int c = (t & 15) << 2;   // 0..60
#pragma unroll
  for (int p = 0; p < 4; p++) {
    const int row = r + p * 16;
    const float4 v = *(const float4*)(Wp + (size_t)row * N + c);
    tile[row][c + 0] = v.x; tile[row][c + 1] = v.y;
    tile[row][c + 2] = v.z; tile[row][c + 3] = v.w;
  }
  __syncthreads();
  u16* WTp = WT + ((size_t)e * N + n0) * K + k0;
#pragma unroll
  for (int p = 0; p < 4; p++) {
    const int row = r + p * 16;  // n index within tile
    u32 lo = (u32)f2bf(tile[c + 0][row]) | ((u32)f2bf(tile[c + 1][row]) << 16);
    u32 hi = (u32)f2bf(tile[c + 2][row]) | ((u32)f2bf(tile[c + 3][row]) << 16);
    *(uint2*)(WTp + (size_t)row * K + c) = make_uint2(lo, hi);
  }
}

// ---------------- Wg[m][512][18] fp32 -> WgT[m][18][512] bf16 -------------------------
__global__ __launch_bounds__(256) void wgtrans_kernel(const float* __restrict__ Wg,
                                                      u16* __restrict__ WgT, int total) {
  int idx = blockIdx.x * 256 + threadIdx.x;
  if (idx >= total) return;
  int d = idx & 511;
  int r = idx >> 9;
  int e = r % 18;
  int m = r / 18;
  WgT[idx] = f2bf(Wg[((size_t)(m * 512 + d)) * 18 + e]);
}

// ---------------- elementwise fp32 -> bf16 --------------------------------------------
__global__ __launch_bounds__(256) void cvtbf_kernel(const float* __restrict__ src,
                                                    u16* __restrict__ dst, int n4) {
  int i = blockIdx.x * 256 + threadIdx.x;
  if (i >= n4) return;
  float4 v = ((const float4*)src)[i];
  u32 lo = (u32)f2bf(v.x) | ((u32)f2bf(v.y) << 16);
  u32 hi = (u32)f2bf(v.z) | ((u32)f2bf(v.w) << 16);
  ((uint2*)dst)[i] = make_uint2(lo, hi);
}

// ---------------- MFMA GEMM: C[r][n] (+bias[n]) = A[r][:] * BT[n][:]^T ----------------
// A bf16 rows (batch), BT bf16 [e][N][K]; 128x128 tile, BK=64, 4 waves 2x2, 4x4 mfma/wave
template <bool RELU_BF16_OUT>
__global__ __launch_bounds__(256, 3) void gemm_kernel(
    const u16* __restrict__ A, const u16* __restrict__ BT,
    const float* __restrict__ bias, void* __restrict__ Cout,
    int lda, int a_shift, int a_mul, int ldc, int c_mul, int N, int K) {
  __shared__ __align__(16) u16 As[128 * 64];
  __shared__ __align__(16) u16 Bs[128 * 64];

  const int tid = threadIdx.x;
  const int lane = tid & 63;
  const int wave = tid >> 6;
  const int e = blockIdx.y;
  const int mt = blockIdx.x & 7;   // M = 1024 always -> 8 row tiles
  const int nt = blockIdx.x >> 3;
  const int m0 = mt << 7, n0 = nt << 7;

  const u16* Aexp = A + (size_t)((e >> a_shift) * a_mul);
  const u16* Bexp = BT + (size_t)e * (size_t)N * (size_t)K;

  // staging: chunk c (of 16) = 1KB = 8 rows; lane l -> row c*8 + l/8, swizzled col group
  const int colsw = (((lane & 7) ^ ((lane >> 3) & 7)) << 3);
  const u16* aptr[4];
  const u16* bptr[4];
  u16* lA[4];
  u16* lB[4];
#pragma unroll
  for (int i = 0; i < 4; i++) {
    const int cch = wave * 4 + i;
    const int row = cch * 8 + (lane >> 3);
    aptr[i] = Aexp + (size_t)(m0 + row) * lda + colsw;
    bptr[i] = Bexp + (size_t)(n0 + row) * K + colsw;
    lA[i] = As + cch * 512;
    lB[i] = Bs + cch * 512;
  }

  floatx4 acc[4][4];
#pragma unroll
  for (int i = 0; i < 4; i++)
#pragma unroll
    for (int j = 0; j < 4; j++) acc[i][j] = (floatx4){0.f, 0.f, 0.f, 0.f};

  const int wm = (wave & 1) << 6;
  const int wn = (wave >> 1) << 6;
  const int r15 = lane & 15;
  const int quad = lane >> 4;

  // fragment LDS offsets (elements), substep s=1 is ^32 (xor-swizzle is linear)
  int aoff[4], boff[4];
#pragma unroll
  for (int i = 0; i < 4; i++) {
    const int ra = wm + i * 16 + r15;
    aoff[i] = ra * 64 + ((quad ^ (ra & 7)) << 3);
    const int rb = wn + i * 16 + r15;
    boff[i] = rb * 64 + ((quad ^ (rb & 7)) << 3);
  }

  for (int k0 = 0; k0 < K; k0 += 64) {
    __syncthreads();
#pragma unroll
    for (int i = 0; i < 4; i++) GLOAD_LDS16(aptr[i] + k0, lA[i]);
#pragma unroll
    for (int i = 0; i < 4; i++) GLOAD_LDS16(bptr[i] + k0, lB[i]);
    __syncthreads();
#pragma unroll
    for (int s = 0; s < 2; s++) {
      short8 af[4], bfr[4];
#pragma unroll
      for (int i = 0; i < 4; i++) af[i] = *(const short8*)(As + (aoff[i] ^ (s << 5)));
#pragma unroll
      for (int j = 0; j < 4; j++) bfr[j] = *(const short8*)(Bs + (boff[j] ^ (s << 5)));
#pragma unroll
      for (int i = 0; i < 4; i++)
#pragma unroll
        for (int j = 0; j < 4; j++)
          acc[i][j] = __builtin_amdgcn_mfma_f32_16x16x32_bf16(af[i], bfr[j], acc[i][j], 0, 0, 0);
    }
  }

  const int ccol0 = n0 + wn + r15;
  const int crow0 = m0 + wm + quad * 4;
  float bv[4];
#pragma unroll
  for (int j = 0; j < 4; j++) bv[j] = bias[e * N + ccol0 + j * 16];

  if constexpr (RELU_BF16_OUT) {
    u16* Co = (u16*)Cout + (size_t)e * c_mul;
#pragma unroll
    for (int i = 0; i < 4; i++)
#pragma unroll
      for (int r = 0; r < 4; r++) {
        const size_t rowoff = (size_t)(crow0 + i * 16 + r) * ldc;
#pragma unroll
        for (int j = 0; j < 4; j++) {
          float v = acc[i][j][r] + bv[j];
          v = v > 0.f ? v : 0.f;
          Co[rowoff + ccol0 + j * 16] = f2bf(v);
        }
      }
  } else {
    float* Co = (float*)Cout + (size_t)e * c_mul;
#pragma unroll
    for (int i = 0; i < 4; i++)
#pragma unroll
      for (int r = 0; r < 4; r++) {
        const size_t rowoff = (size_t)(crow0 + i * 16 + r) * ldc;
#pragma unroll
        for (int j = 0; j < 4; j++) Co[rowoff + ccol0 + j * 16] = acc[i][j][r] + bv[j];
      }
  }
}

// ---------------- gating: wsm[b][m][18] = softmax(x[b,m,:]·Wg[m] + bg[m]) + add -------
// grid (B/8, M); wave handles 2 batches; x bf16 [B][9][512]; WgT bf16 [M][18][512]
template <int M, int LAYER>
__global__ __launch_bounds__(256) void gating_kernel(
    const u16* __restrict__ xbf, const u16* __restrict__ WgT,
    const float* __restrict__ bg, const float* __restrict__ sew_task,
    const float* __restrict__ sew_shared, float* __restrict__ wsm) {
  const int lane = threadIdx.x & 63;
  const int wave = threadIdx.x >> 6;
  const int m = blockIdx.y;
  const int b0 = blockIdx.x * 8 + wave * 2;

  float xa[8], xb[8];
  bf8_to_f(xbf + (size_t)b0 * 4608 + m * 512 + lane * 8, xa);
  bf8_to_f(xbf + (size_t)(b0 + 1) * 4608 + m * 512 + lane * 8, xb);

  float lg0[18], lg1[18];
#pragma unroll
  for (int e = 0; e < 18; e++) {
    float w[8];
    bf8_to_f(WgT + ((size_t)m * 18 + e) * 512 + lane * 8, w);
    float s0 = 0.f, s1 = 0.f;
#pragma unroll
    for (int i = 0; i < 8; i++) { s0 = fmaf(w[i], xa[i], s0); s1 = fmaf(w[i], xb[i], s1); }
#pragma unroll
    for (int off = 1; off < 64; off <<= 1) {
      s0 += __shfl_xor(s0, off, 64);
      s1 += __shfl_xor(s1, off, 64);
    }
    const float bgv = bg[m * 18 + e];
    lg0[e] = s0 + bgv;
    lg1[e] = s1 + bgv;
  }
  // per-lane redundant softmax over the 18 register values
  float mx0 = lg0[0], mx1 = lg1[0];
#pragma unroll
  for (int e = 1; e < 18; e++) { mx0 = fmaxf(mx0, lg0[e]); mx1 = fmaxf(mx1, lg1[e]); }
  float sum0 = 0.f, sum1 = 0.f;
#pragma unroll
  for (int e = 0; e < 18; e++) { sum0 += __expf(lg0[e] - mx0); sum1 += __expf(lg1[e] - mx1); }
  float my0 = lg0[0], my1 = lg1[0];
#pragma unroll
  for (int e = 1; e < 18; e++)
    if (lane == e) { my0 = lg0[e]; my1 = lg1[e]; }
  float w0 = __expf(my0 - mx0) / sum0;
  float w1 = __expf(my1 - mx1) / sum1;
  if ((lane >> 1) == m) {
    float add;
    if (M == 9 && m == 8) add = sew_shared[lane & 1];
    else                  add = sew_task[m * 4 + 2 * LAYER + (lane & 1)];
    w0 += add; w1 += add;
  }
  if (lane < 18) {
    wsm[((size_t)b0 * M + m) * 18 + lane] = w0;
    wsm[((size_t)(b0 + 1) * M + m) * 18 + lane] = w1;
  }
}

// ---------------- weighted sum: out[b][m][:] = sum_e wsm[b][m][e] * eo[b][e][:] -------
// grid (B/2); 256 thr: local batch = t>>7, float4 slice s = t&127; accs in registers
template <int M, bool BF16OUT>
__global__ __launch_bounds__(256) void wsum_kernel(
    const float* __restrict__ eo, const float* __restrict__ wsm,
    float* __restrict__ outf, u16* __restrict__ outb) {
  __shared__ float ws[2 * M * 18];
  const int t = threadIdx.x;
  const int b0 = blockIdx.x * 2;
  for (int i = t; i < 2 * M * 18; i += 256) ws[i] = wsm[(size_t)b0 * M * 18 + i];
  __syncthreads();
  const int lb = t >> 7;
  const int s = t & 127;
  const int b = b0 + lb;
  const float* eob = eo + (size_t)b * 9216 + s * 4;
  const float* wr = ws + lb * M * 18;

  float4 acc[M];
#pragma unroll
  for (int m = 0; m < M; m++) acc[m] = make_float4(0.f, 0.f, 0.f, 0.f);
#pragma unroll
  for (int e = 0; e < 18; e++) {
    const float4 v = *(const float4*)(eob + e * 512);
#pragma unroll
    for (int m = 0; m < M; m++) {
      const float w = wr[m * 18 + e];
      acc[m].x = fmaf(w, v.x, acc[m].x);
      acc[m].y = fmaf(w, v.y, acc[m].y);
      acc[m].z = fmaf(w, v.z, acc[m].z);
      acc[m].w = fmaf(w, v.w, acc[m].w);
    }
  }
  if constexpr (BF16OUT) {
    u16* ob = outb + (size_t)b * 4608 + s * 4;
#pragma unroll
    for (int m = 0; m < M; m++) {
      u32 lo = (u32)f2bf(acc[m].x) | ((u32)f2bf(acc[m].y) << 16);
      u32 hi = (u32)f2bf(acc[m].z) | ((u32)f2bf(acc[m].w) << 16);
      *(uint2*)(ob + m * 512) = make_uint2(lo, hi);
    }
  } else {
    float* ob = outf + (size_t)b * (M * 512) + s * 4;
#pragma unroll
    for (int m = 0; m < M; m++) *(float4*)(ob + m * 512) = acc[m];
  }
}

extern "C" void kernel_launch(void* const* d_in, const int* in_sizes, int n_in,
                              void* d_out, int out_size, void* d_ws, size_t ws_size,
                              hipStream_t stream) {
  const float* x0   = (const float*)d_in[0];
  const float* W1_0 = (const float*)d_in[1];
  const float* b1_0 = (const float*)d_in[2];
  const float* W2_0 = (const float*)d_in[3];
  const float* b2_0 = (const float*)d_in[4];
  const float* Wg_0 = (const float*)d_in[5];
  const float* bg_0 = (const float*)d_in[6];
  const float* W1_1 = (const float*)d_in[7];
  const float* b1_1 = (const float*)d_in[8];
  const float* W2_1 = (const float*)d_in[9];
  const float* b2_1 = (const float*)d_in[10];
  const float* Wg_1 = (const float*)d_in[11];
  const float* bg_1 = (const float*)d_in[12];
  const float* sewt = (const float*)d_in[13];
  const float* sews = (const float*)d_in[14];
  float* out = (float*)d_out;

  char* p = (char*)d_ws;
  auto take = [&](size_t n) { char* r = p; p += (n + 255) & ~(size_t)255; return r; };
  u16*   x0bf = (u16*)take(4718592ull * 2);     // [B][9][512] bf16
  u16*   W1T0 = (u16*)take(9437184ull * 2);     // [18][1024][512] bf16
  u16*   W2T0 = (u16*)take(9437184ull * 2);     // [18][512][1024] bf16
  u16*   W1T1 = (u16*)take(9437184ull * 2);
  u16*   W2T1 = (u16*)take(9437184ull * 2);
  u16*   WgT0 = (u16*)take(82944ull * 2);       // [9][18][512] bf16
  u16*   WgT1 = (u16*)take(73728ull * 2);       // [8][18][512] bf16
  u16*   hbf  = (u16*)take(18874368ull * 2);    // [B][18][1024] bf16
  float* eo   = (float*)take(9437184ull * 4);   // [B][18][512] fp32
  u16*   x1bf = (u16*)take(4718592ull * 2);     // [B][9][512] bf16
  float* wsm0 = (float*)take(165888ull * 4);    // [B][9][18] fp32
  float* wsm1 = (float*)take(147456ull * 4);    // [B][8][18] fp32

  dim3 blk(256);
  // weight transposes + converts
  wtrans_kernel<<<dim3(16, 8, 18), blk, 0, stream>>>(W1_0, W1T0, 512, 1024);
  wtrans_kernel<<<dim3(8, 16, 18), blk, 0, stream>>>(W2_0, W2T0, 1024, 512);
  wtrans_kernel<<<dim3(16, 8, 18), blk, 0, stream>>>(W1_1, W1T1, 512, 1024);
  wtrans_kernel<<<dim3(8, 16, 18), blk, 0, stream>>>(W2_1, W2T1, 1024, 512);
  wgtrans_kernel<<<dim3(324), blk, 0, stream>>>(Wg_0, WgT0, 82944);
  wgtrans_kernel<<<dim3(288), blk, 0, stream>>>(Wg_1, WgT1, 73728);
  cvtbf_kernel<<<dim3(4608), blk, 0, stream>>>(x0, x0bf, 1179648);

  // layer 0
  gating_kernel<9, 0><<<dim3(128, 9), blk, 0, stream>>>(x0bf, WgT0, bg_0, sewt, sews, wsm0);
  gemm_kernel<true><<<dim3(64, 18), blk, 0, stream>>>(
      x0bf, W1T0, b1_0, (void*)hbf, 4608, 1, 512, 18432, 1024, 1024, 512);
  gemm_kernel<false><<<dim3(32, 18), blk, 0, stream>>>(
      hbf, W2T0, b2_0, (void*)eo, 18432, 0, 1024, 9216, 512, 512, 1024);
  wsum_kernel<9, true><<<dim3(512), blk, 0, stream>>>(eo, wsm0, nullptr, x1bf);

  // layer 1
  gating_kernel<8, 1><<<dim3(128, 8), blk, 0, stream>>>(x1bf, WgT1, bg_1, sewt, sews, wsm1);
  gemm_kernel<true><<<dim3(64, 18), blk, 0, stream>>>(
      x1bf, W1T1, b1_1, (void*)hbf, 4608, 1, 512, 18432, 1024, 1024, 512);
  gemm_kernel<false><<<dim3(32, 18), blk, 0, stream>>>(
      hbf, W2T1, b2_1, (void*)eo, 18432, 0, 1024, 9216, 512, 512, 1024);
  wsum_kernel<8, false><<<dim3(512), blk, 0, stream>>>(eo, wsm1, out, nullptr);
}

// Round 5
// 392.479 us; speedup vs baseline: 1.1843x; 1.0366x over previous
//
#include <hip/hip_runtime.h>

typedef unsigned short u16;
typedef unsigned int u32;
typedef __attribute__((ext_vector_type(8))) short short8;
typedef __attribute__((ext_vector_type(4))) float floatx4;

#define GLOAD_LDS16(gp, lp)                                                              \
  __builtin_amdgcn_global_load_lds((const __attribute__((address_space(1))) void*)(gp),  \
                                   (__attribute__((address_space(3))) void*)(lp), 16, 0, 0)

__device__ __forceinline__ u16 f2bf(float f) {
  u32 u = __float_as_uint(f);
  u += 0x7fffu + ((u >> 16) & 1u);   // round-to-nearest-even
  return (u16)(u >> 16);
}

__device__ __forceinline__ void bf8_to_f(const u16* p, float* o) {
  const uint4 v = *(const uint4*)p;
  const u32 a[4] = {v.x, v.y, v.z, v.w};
#pragma unroll
  for (int i = 0; i < 4; i++) {
    o[2 * i]     = __uint_as_float(a[i] << 16);
    o[2 * i + 1] = __uint_as_float(a[i] & 0xffff0000u);
  }
}

// ------ merged transpose + fp32->bf16:  4 tensors W[e][K][N] -> WT[e][N][K] -----------
// grid (16,16,72): z -> tensor t = z/18, expert e = z%18; W1:(K=512,N=1024) W2:(1024,512)
__global__ __launch_bounds__(256) void wtrans4_kernel(
    const float* __restrict__ W1a, const float* __restrict__ W2a,
    const float* __restrict__ W1b, const float* __restrict__ W2b,
    u16* __restrict__ T1a, u16* __restrict__ T2a,
    u16* __restrict__ T1b, u16* __restrict__ T2b) {
  const int z = blockIdx.z;
  const int tsel = z / 18;
  const int e = z % 18;
  const int K = (tsel & 1) ? 1024 : 512;
  const int N = (tsel & 1) ? 512 : 1024;
  const int n0 = blockIdx.x * 64;
  const int k0 = blockIdx.y * 64;
  if (n0 >= N || k0 >= K) return;
  const float* W = (tsel == 0) ? W1a : (tsel == 1) ? W2a : (tsel == 2) ? W1b : W2b;
  u16* WT = (tsel == 0) ? T1a : (tsel == 1) ? T2a : (tsel == 2) ? T1b : T2b;

  __shared__ float tile[64][65];
  const int t = threadIdx.x;
  const float* Wp = W + ((size_t)e * K + k0) * N + n0;
  const int r = t >> 4;          // 0..15
  const int c = (t & 15) << 2;   // 0..60
#pragma unroll
  for (int p = 0; p < 4; p++) {
    const int row = r + p * 16;
    const float4 v = *(const float4*)(Wp + (size_t)row * N + c);
    tile[row][c + 0] = v.x; tile[row][c + 1] = v.y;
    tile[row][c + 2] = v.z; tile[row][c + 3] = v.w;
  }
  __syncthreads();
  u16* WTp = WT + ((size_t)e * N + n0) * K + k0;
#pragma unroll
  for (int p = 0; p < 4; p++) {
    const int row = r + p * 16;  // n index within tile
    u32 lo = (u32)f2bf(tile[c + 0][row]) | ((u32)f2bf(tile[c + 1][row]) << 16);
    u32 hi = (u32)f2bf(tile[c + 2][row]) | ((u32)f2bf(tile[c + 3][row]) << 16);
    *(uint2*)(WTp + (size_t)row * K + c) = make_uint2(lo, hi);
  }
}

// ---------------- Wg[m][512][18] fp32 -> WgT[m][18][512] bf16, both layers ------------
__global__ __launch_bounds__(256) void wgtrans_kernel(const float* __restrict__ Wg0,
                                                      const float* __restrict__ Wg1,
                                                      u16* __restrict__ WgT0,
                                                      u16* __restrict__ WgT1) {
  int idx = blockIdx.x * 256 + threadIdx.x;
  const float* Wg = Wg0;
  u16* WgT = WgT0;
  if (idx >= 82944) {
    idx -= 82944;
    if (idx >= 73728) return;
    Wg = Wg1; WgT = WgT1;
  }
  int d = idx & 511;
  int r = idx >> 9;
  int e = r % 18;
  int m = r / 18;
  WgT[idx] = f2bf(Wg[((size_t)(m * 512 + d)) * 18 + e]);
}

// ---------------- elementwise fp32 -> bf16 --------------------------------------------
__global__ __launch_bounds__(256) void cvtbf_kernel(const float* __restrict__ src,
                                                    u16* __restrict__ dst, int n4) {
  int i = blockIdx.x * 256 + threadIdx.x;
  if (i >= n4) return;
  float4 v = ((const float4*)src)[i];
  u32 lo = (u32)f2bf(v.x) | ((u32)f2bf(v.y) << 16);
  u32 hi = (u32)f2bf(v.z) | ((u32)f2bf(v.w) << 16);
  ((uint2*)dst)[i] = make_uint2(lo, hi);
}

// ---------------- MFMA GEMM: C[r][n] (+bias[n]) = A[r][:] * BT[n][:]^T ----------------
// 1D grid, XCD-swizzled: xcd=id&7 gets contiguous same-expert block range so B/A tiles
// are reused within one per-XCD L2. nshift = log2(blocks per expert).
template <bool RELU_BF16_OUT>
__global__ __launch_bounds__(256, 3) void gemm_kernel(
    const u16* __restrict__ A, const u16* __restrict__ BT,
    const float* __restrict__ bias, void* __restrict__ Cout,
    int lda, int a_shift, int a_mul, int ldc, int c_mul, int N, int K, int nshift) {
  __shared__ __align__(16) u16 As[128 * 64];
  __shared__ __align__(16) u16 Bs[128 * 64];

  const int tid = threadIdx.x;
  const int lane = tid & 63;
  const int wave = tid >> 6;

  const int L = blockIdx.x;
  const int per_xcd = gridDim.x >> 3;
  const int g = (L & 7) * per_xcd + (L >> 3);
  const int e = g >> nshift;
  const int wb = g & ((1 << nshift) - 1);
  const int mt = wb & 7;           // M = 1024 always -> 8 row tiles (fastest: share B)
  const int nt = wb >> 3;
  const int m0 = mt << 7, n0 = nt << 7;

  const u16* Aexp = A + (size_t)((e >> a_shift) * a_mul);
  const u16* Bexp = BT + (size_t)e * (size_t)N * (size_t)K;

  // staging: chunk c (of 16) = 1KB = 8 rows; lane l -> row c*8 + l/8, swizzled col group
  const int colsw = (((lane & 7) ^ ((lane >> 3) & 7)) << 3);
  const u16* aptr[4];
  const u16* bptr[4];
  u16* lA[4];
  u16* lB[4];
#pragma unroll
  for (int i = 0; i < 4; i++) {
    const int cch = wave * 4 + i;
    const int row = cch * 8 + (lane >> 3);
    aptr[i] = Aexp + (size_t)(m0 + row) * lda + colsw;
    bptr[i] = Bexp + (size_t)(n0 + row) * K + colsw;
    lA[i] = As + cch * 512;
    lB[i] = Bs + cch * 512;
  }

  floatx4 acc[4][4];
#pragma unroll
  for (int i = 0; i < 4; i++)
#pragma unroll
    for (int j = 0; j < 4; j++) acc[i][j] = (floatx4){0.f, 0.f, 0.f, 0.f};

  const int wm = (wave & 1) << 6;
  const int wn = (wave >> 1) << 6;
  const int r15 = lane & 15;
  const int quad = lane >> 4;

  // fragment LDS offsets (elements), substep s=1 is ^32 (xor-swizzle is linear)
  int aoff[4], boff[4];
#pragma unroll
  for (int i = 0; i < 4; i++) {
    const int ra = wm + i * 16 + r15;
    aoff[i] = ra * 64 + ((quad ^ (ra & 7)) << 3);
    const int rb = wn + i * 16 + r15;
    boff[i] = rb * 64 + ((quad ^ (rb & 7)) << 3);
  }

  for (int k0 = 0; k0 < K; k0 += 64) {
    __syncthreads();
#pragma unroll
    for (int i = 0; i < 4; i++) GLOAD_LDS16(aptr[i] + k0, lA[i]);
#pragma unroll
    for (int i = 0; i < 4; i++) GLOAD_LDS16(bptr[i] + k0, lB[i]);
    __syncthreads();
#pragma unroll
    for (int s = 0; s < 2; s++) {
      short8 af[4], bfr[4];
#pragma unroll
      for (int i = 0; i < 4; i++) af[i] = *(const short8*)(As + (aoff[i] ^ (s << 5)));
#pragma unroll
      for (int j = 0; j < 4; j++) bfr[j] = *(const short8*)(Bs + (boff[j] ^ (s << 5)));
#pragma unroll
      for (int i = 0; i < 4; i++)
#pragma unroll
        for (int j = 0; j < 4; j++)
          acc[i][j] = __builtin_amdgcn_mfma_f32_16x16x32_bf16(af[i], bfr[j], acc[i][j], 0, 0, 0);
    }
  }

  const int ccol0 = n0 + wn + r15;
  const int crow0 = m0 + wm + quad * 4;
  float bv[4];
#pragma unroll
  for (int j = 0; j < 4; j++) bv[j] = bias[e * N + ccol0 + j * 16];

  if constexpr (RELU_BF16_OUT) {
    u16* Co = (u16*)Cout + (size_t)e * c_mul;
#pragma unroll
    for (int i = 0; i < 4; i++)
#pragma unroll
      for (int r = 0; r < 4; r++) {
        const size_t rowoff = (size_t)(crow0 + i * 16 + r) * ldc;
#pragma unroll
        for (int j = 0; j < 4; j++) {
          float v = acc[i][j][r] + bv[j];
          v = v > 0.f ? v : 0.f;
          Co[rowoff + ccol0 + j * 16] = f2bf(v);
        }
      }
  } else {
    float* Co = (float*)Cout + (size_t)e * c_mul;
#pragma unroll
    for (int i = 0; i < 4; i++)
#pragma unroll
      for (int r = 0; r < 4; r++) {
        const size_t rowoff = (size_t)(crow0 + i * 16 + r) * ldc;
#pragma unroll
        for (int j = 0; j < 4; j++) Co[rowoff + ccol0 + j * 16] = acc[i][j][r] + bv[j];
      }
  }
}

// ---------------- gating: wsm[b][m][18] = softmax(x[b,m,:]·Wg[m] + bg[m]) + add -------
// grid (B/8, M); wave handles 2 batches; x bf16 [B][9][512]; WgT bf16 [M][18][512]
template <int M, int LAYER>
__global__ __launch_bounds__(256) void gating_kernel(
    const u16* __restrict__ xbf, const u16* __restrict__ WgT,
    const float* __restrict__ bg, const float* __restrict__ sew_task,
    const float* __restrict__ sew_shared, float* __restrict__ wsm) {
  const int lane = threadIdx.x & 63;
  const int wave = threadIdx.x >> 6;
  const int m = blockIdx.y;
  const int b0 = blockIdx.x * 8 + wave * 2;

  float xa[8], xb[8];
  bf8_to_f(xbf + (size_t)b0 * 4608 + m * 512 + lane * 8, xa);
  bf8_to_f(xbf + (size_t)(b0 + 1) * 4608 + m * 512 + lane * 8, xb);

  float lg0[18], lg1[18];
#pragma unroll
  for (int e = 0; e < 18; e++) {
    float w[8];
    bf8_to_f(WgT + ((size_t)m * 18 + e) * 512 + lane * 8, w);
    float s0 = 0.f, s1 = 0.f;
#pragma unroll
    for (int i = 0; i < 8; i++) { s0 = fmaf(w[i], xa[i], s0); s1 = fmaf(w[i], xb[i], s1); }
#pragma unroll
    for (int off = 1; off < 64; off <<= 1) {
      s0 += __shfl_xor(s0, off, 64);
      s1 += __shfl_xor(s1, off, 64);
    }
    const float bgv = bg[m * 18 + e];
    lg0[e] = s0 + bgv;
    lg1[e] = s1 + bgv;
  }
  // per-lane redundant softmax over the 18 register values
  float mx0 = lg0[0], mx1 = lg1[0];
#pragma unroll
  for (int e = 1; e < 18; e++) { mx0 = fmaxf(mx0, lg0[e]); mx1 = fmaxf(mx1, lg1[e]); }
  float sum0 = 0.f, sum1 = 0.f;
#pragma unroll
  for (int e = 0; e < 18; e++) { sum0 += __expf(lg0[e] - mx0); sum1 += __expf(lg1[e] - mx1); }
  float my0 = lg0[0], my1 = lg1[0];
#pragma unroll
  for (int e = 1; e < 18; e++)
    if (lane == e) { my0 = lg0[e]; my1 = lg1[e]; }
  float w0 = __expf(my0 - mx0) / sum0;
  float w1 = __expf(my1 - mx1) / sum1;
  if ((lane >> 1) == m) {
    float add;
    if (M == 9 && m == 8) add = sew_shared[lane & 1];
    else                  add = sew_task[m * 4 + 2 * LAYER + (lane & 1)];
    w0 += add; w1 += add;
  }
  if (lane < 18) {
    wsm[((size_t)b0 * M + m) * 18 + lane] = w0;
    wsm[((size_t)(b0 + 1) * M + m) * 18 + lane] = w1;
  }
}

// ---------------- weighted sum: out[b][m][:] = sum_e wsm[b][m][e] * eo[b][e][:] -------
// grid (B/2); 256 thr: local batch = t>>7, float4 slice s = t&127; accs in registers
template <int M, bool BF16OUT>
__global__ __launch_bounds__(256) void wsum_kernel(
    const float* __restrict__ eo, const float* __restrict__ wsm,
    float* __restrict__ outf, u16* __restrict__ outb) {
  __shared__ float ws[2 * M * 18];
  const int t = threadIdx.x;
  const int b0 = blockIdx.x * 2;
  for (int i = t; i < 2 * M * 18; i += 256) ws[i] = wsm[(size_t)b0 * M * 18 + i];
  __syncthreads();
  const int lb = t >> 7;
  const int s = t & 127;
  const int b = b0 + lb;
  const float* eob = eo + (size_t)b * 9216 + s * 4;
  const float* wr = ws + lb * M * 18;

  float4 acc[M];
#pragma unroll
  for (int m = 0; m < M; m++) acc[m] = make_float4(0.f, 0.f, 0.f, 0.f);
#pragma unroll
  for (int e = 0; e < 18; e++) {
    const float4 v = *(const float4*)(eob + e * 512);
#pragma unroll
    for (int m = 0; m < M; m++) {
      const float w = wr[m * 18 + e];
      acc[m].x = fmaf(w, v.x, acc[m].x);
      acc[m].y = fmaf(w, v.y, acc[m].y);
      acc[m].z = fmaf(w, v.z, acc[m].z);
      acc[m].w = fmaf(w, v.w, acc[m].w);
    }
  }
  if constexpr (BF16OUT) {
    u16* ob = outb + (size_t)b * 4608 + s * 4;
#pragma unroll
    for (int m = 0; m < M; m++) {
      u32 lo = (u32)f2bf(acc[m].x) | ((u32)f2bf(acc[m].y) << 16);
      u32 hi = (u32)f2bf(acc[m].z) | ((u32)f2bf(acc[m].w) << 16);
      *(uint2*)(ob + m * 512) = make_uint2(lo, hi);
    }
  } else {
    float* ob = outf + (size_t)b * (M * 512) + s * 4;
#pragma unroll
    for (int m = 0; m < M; m++) *(float4*)(ob + m * 512) = acc[m];
  }
}

extern "C" void kernel_launch(void* const* d_in, const int* in_sizes, int n_in,
                              void* d_out, int out_size, void* d_ws, size_t ws_size,
                              hipStream_t stream) {
  const float* x0   = (const float*)d_in[0];
  const float* W1_0 = (const float*)d_in[1];
  const float* b1_0 = (const float*)d_in[2];
  const float* W2_0 = (const float*)d_in[3];
  const float* b2_0 = (const float*)d_in[4];
  const float* Wg_0 = (const float*)d_in[5];
  const float* bg_0 = (const float*)d_in[6];
  const float* W1_1 = (const float*)d_in[7];
  const float* b1_1 = (const float*)d_in[8];
  const float* W2_1 = (const float*)d_in[9];
  const float* b2_1 = (const float*)d_in[10];
  const float* Wg_1 = (const float*)d_in[11];
  const float* bg_1 = (const float*)d_in[12];
  const float* sewt = (const float*)d_in[13];
  const float* sews = (const float*)d_in[14];
  float* out = (float*)d_out;

  char* p = (char*)d_ws;
  auto take = [&](size_t n) { char* r = p; p += (n + 255) & ~(size_t)255; return r; };
  u16*   x0bf = (u16*)take(4718592ull * 2);     // [B][9][512] bf16
  u16*   W1T0 = (u16*)take(9437184ull * 2);     // [18][1024][512] bf16
  u16*   W2T0 = (u16*)take(9437184ull * 2);     // [18][512][1024] bf16
  u16*   W1T1 = (u16*)take(9437184ull * 2);
  u16*   W2T1 = (u16*)take(9437184ull * 2);
  u16*   WgT0 = (u16*)take(82944ull * 2);       // [9][18][512] bf16
  u16*   WgT1 = (u16*)take(73728ull * 2);       // [8][18][512] bf16
  u16*   hbf  = (u16*)take(18874368ull * 2);    // [B][18][1024] bf16
  float* eo   = (float*)take(9437184ull * 4);   // [B][18][512] fp32
  u16*   x1bf = (u16*)take(4718592ull * 2);     // [B][9][512] bf16
  float* wsm0 = (float*)take(165888ull * 4);    // [B][9][18] fp32
  float* wsm1 = (float*)take(147456ull * 4);    // [B][8][18] fp32

  dim3 blk(256);
  // weight transposes + converts (merged)
  wtrans4_kernel<<<dim3(16, 16, 72), blk, 0, stream>>>(W1_0, W2_0, W1_1, W2_1,
                                                       W1T0, W2T0, W1T1, W2T1);
  wgtrans_kernel<<<dim3(613), blk, 0, stream>>>(Wg_0, Wg_1, WgT0, WgT1);
  cvtbf_kernel<<<dim3(4608), blk, 0, stream>>>(x0, x0bf, 1179648);

  // layer 0
  gating_kernel<9, 0><<<dim3(128, 9), blk, 0, stream>>>(x0bf, WgT0, bg_0, sewt, sews, wsm0);
  gemm_kernel<true><<<dim3(1152), blk, 0, stream>>>(
      x0bf, W1T0, b1_0, (void*)hbf, 4608, 1, 512, 18432, 1024, 1024, 512, 6);
  gemm_kernel<false><<<dim3(576), blk, 0, stream>>>(
      hbf, W2T0, b2_0, (void*)eo, 18432, 0, 1024, 9216, 512, 512, 1024, 5);
  wsum_kernel<9, true><<<dim3(512), blk, 0, stream>>>(eo, wsm0, nullptr, x1bf);

  // layer 1
  gating_kernel<8, 1><<<dim3(128, 8), blk, 0, stream>>>(x1bf, WgT1, bg_1, sewt, sews, wsm1);
  gemm_kernel<true><<<dim3(1152), blk, 0, stream>>>(
      x1bf, W1T1, b1_1, (void*)hbf, 4608, 1, 512, 18432, 1024, 1024, 512, 6);
  gemm_kernel<false><<<dim3(576), blk, 0, stream>>>(
      hbf, W2T1, b2_1, (void*)eo, 18432, 0, 1024, 9216, 512, 512, 1024, 5);
  wsum_kernel<8, false><<<dim3(512), blk, 0, stream>>>(eo, wsm1, out, nullptr);
}

// Round 6
// 366.858 us; speedup vs baseline: 1.2670x; 1.0698x over previous
//
#include <hip/hip_runtime.h>

typedef unsigned short u16;
typedef unsigned int u32;
typedef __attribute__((ext_vector_type(8))) short short8;
typedef __attribute__((ext_vector_type(4))) float floatx4;

#define GLOAD_LDS16(gp, lp)                                                              \
  __builtin_amdgcn_global_load_lds((const __attribute__((address_space(1))) void*)(gp),  \
                                   (__attribute__((address_space(3))) void*)(lp), 16, 0, 0)

__device__ __forceinline__ u16 f2bf(float f) {
  u32 u = __float_as_uint(f);
  u += 0x7fffu + ((u >> 16) & 1u);   // round-to-nearest-even
  return (u16)(u >> 16);
}

__device__ __forceinline__ void bf8_to_f(const u16* p, float* o) {
  const uint4 v = *(const uint4*)p;
  const u32 a[4] = {v.x, v.y, v.z, v.w};
#pragma unroll
  for (int i = 0; i < 4; i++) {
    o[2 * i]     = __uint_as_float(a[i] << 16);
    o[2 * i + 1] = __uint_as_float(a[i] & 0xffff0000u);
  }
}

// ------ merged prep: wtrans x4 tensors + wgtrans x2 + cvtbf(x0), 1D heterogeneous grid
// blocks [0,9216): transpose+cvt W tiles; [9216,9828): Wg; [9828,14436): x0 cvt
__global__ __launch_bounds__(256) void prep_kernel(
    const float* __restrict__ W1a, const float* __restrict__ W2a,
    const float* __restrict__ W1b, const float* __restrict__ W2b,
    u16* __restrict__ T1a, u16* __restrict__ T2a,
    u16* __restrict__ T1b, u16* __restrict__ T2b,
    const float* __restrict__ Wg0, const float* __restrict__ Wg1,
    u16* __restrict__ WgT0, u16* __restrict__ WgT1,
    const float* __restrict__ x0, u16* __restrict__ x0bf) {
  __shared__ float tile[64][65];
  const int id = blockIdx.x;
  const int t = threadIdx.x;

  if (id < 9216) {
    const int tsel = id / 2304;
    const int rem = id % 2304;
    const int e = rem >> 7;
    const int t128 = rem & 127;
    const int K = (tsel & 1) ? 1024 : 512;
    const int N = (tsel & 1) ? 512 : 1024;
    const int kt = (tsel & 1) ? (t128 & 15) : (t128 & 7);
    const int nt = (tsel & 1) ? (t128 >> 4) : (t128 >> 3);
    const int k0 = kt * 64, n0 = nt * 64;
    const float* W = (tsel == 0) ? W1a : (tsel == 1) ? W2a : (tsel == 2) ? W1b : W2b;
    u16* WT = (tsel == 0) ? T1a : (tsel == 1) ? T2a : (tsel == 2) ? T1b : T2b;

    const float* Wp = W + ((size_t)e * K + k0) * N + n0;
    const int r = t >> 4;          // 0..15
    const int c = (t & 15) << 2;   // 0..60
#pragma unroll
    for (int p = 0; p < 4; p++) {
      const int row = r + p * 16;
      const float4 v = *(const float4*)(Wp + (size_t)row * N + c);
      tile[row][c + 0] = v.x; tile[row][c + 1] = v.y;
      tile[row][c + 2] = v.z; tile[row][c + 3] = v.w;
    }
    __syncthreads();
    u16* WTp = WT + ((size_t)e * N + n0) * K + k0;
#pragma unroll
    for (int p = 0; p < 4; p++) {
      const int row = r + p * 16;  // n index within tile
      u32 lo = (u32)f2bf(tile[c + 0][row]) | ((u32)f2bf(tile[c + 1][row]) << 16);
      u32 hi = (u32)f2bf(tile[c + 2][row]) | ((u32)f2bf(tile[c + 3][row]) << 16);
      *(uint2*)(WTp + (size_t)row * K + c) = make_uint2(lo, hi);
    }
  } else if (id < 9828) {
    int idx = (id - 9216) * 256 + t;
    const float* Wg = Wg0;
    u16* WgT = WgT0;
    if (idx >= 82944) { idx -= 82944; Wg = Wg1; WgT = WgT1; }
    const int d = idx & 511;
    const int r = idx >> 9;
    const int e = r % 18;
    const int m = r / 18;
    WgT[idx] = f2bf(Wg[((size_t)(m * 512 + d)) * 18 + e]);
  } else {
    const int i = (id - 9828) * 256 + t;   // 4608*256 == 1179648 float4s exactly
    const float4 v = ((const float4*)x0)[i];
    u32 lo = (u32)f2bf(v.x) | ((u32)f2bf(v.y) << 16);
    u32 hi = (u32)f2bf(v.z) | ((u32)f2bf(v.w) << 16);
    ((uint2*)x0bf)[i] = make_uint2(lo, hi);
  }
}

// ---------------- gating body: wsm[b][m][18] = softmax(x[b,m,:]·Wg[m] + bg[m]) + add --
// bid in [0, 128*M); wave handles 2 batches; x bf16 [B][9][512]; WgT bf16 [M][18][512]
template <int M, int LAYER>
__device__ __forceinline__ void gating_body(
    int bid, const u16* __restrict__ xbf, const u16* __restrict__ WgT,
    const float* __restrict__ bg, const float* __restrict__ sew_task,
    const float* __restrict__ sew_shared, float* __restrict__ wsm) {
  const int lane = threadIdx.x & 63;
  const int wave = threadIdx.x >> 6;
  const int m = bid >> 7;
  const int b0 = (bid & 127) * 8 + wave * 2;

  float xa[8], xb[8];
  bf8_to_f(xbf + (size_t)b0 * 4608 + m * 512 + lane * 8, xa);
  bf8_to_f(xbf + (size_t)(b0 + 1) * 4608 + m * 512 + lane * 8, xb);

  float lg0[18], lg1[18];
#pragma unroll
  for (int e = 0; e < 18; e++) {
    float w[8];
    bf8_to_f(WgT + ((size_t)m * 18 + e) * 512 + lane * 8, w);
    float s0 = 0.f, s1 = 0.f;
#pragma unroll
    for (int i = 0; i < 8; i++) { s0 = fmaf(w[i], xa[i], s0); s1 = fmaf(w[i], xb[i], s1); }
#pragma unroll
    for (int off = 1; off < 64; off <<= 1) {
      s0 += __shfl_xor(s0, off, 64);
      s1 += __shfl_xor(s1, off, 64);
    }
    const float bgv = bg[m * 18 + e];
    lg0[e] = s0 + bgv;
    lg1[e] = s1 + bgv;
  }
  float mx0 = lg0[0], mx1 = lg1[0];
#pragma unroll
  for (int e = 1; e < 18; e++) { mx0 = fmaxf(mx0, lg0[e]); mx1 = fmaxf(mx1, lg1[e]); }
  float sum0 = 0.f, sum1 = 0.f;
#pragma unroll
  for (int e = 0; e < 18; e++) { sum0 += __expf(lg0[e] - mx0); sum1 += __expf(lg1[e] - mx1); }
  float my0 = lg0[0], my1 = lg1[0];
#pragma unroll
  for (int e = 1; e < 18; e++)
    if (lane == e) { my0 = lg0[e]; my1 = lg1[e]; }
  float w0 = __expf(my0 - mx0) / sum0;
  float w1 = __expf(my1 - mx1) / sum1;
  if ((lane >> 1) == m) {
    float add;
    if (M == 9 && m == 8) add = sew_shared[lane & 1];
    else                  add = sew_task[m * 4 + 2 * LAYER + (lane & 1)];
    w0 += add; w1 += add;
  }
  if (lane < 18) {
    wsm[((size_t)b0 * M + m) * 18 + lane] = w0;
    wsm[((size_t)(b0 + 1) * M + m) * 18 + lane] = w1;
  }
}

// ---------------- MFMA GEMM (+optional gating tail blocks) ----------------------------
// blocks [0,G): GEMM, XCD-swizzled; blocks [G,...): gating (inputs from prior kernel)
template <bool RELU_BF16_OUT, int M, int LAYER, bool GATE>
__global__ __launch_bounds__(256, 3) void gemm_fused_kernel(
    const u16* __restrict__ A, const u16* __restrict__ BT,
    const float* __restrict__ bias, void* __restrict__ Cout,
    int lda, int a_shift, int a_mul, int ldc, int c_mul, int N, int K, int nshift, int G,
    const u16* __restrict__ WgT, const float* __restrict__ bg,
    const float* __restrict__ sewt, const float* __restrict__ sews,
    float* __restrict__ wsm) {
  if (GATE && (int)blockIdx.x >= G) {
    gating_body<M, LAYER>(blockIdx.x - G, A, WgT, bg, sewt, sews, wsm);
    return;
  }
  __shared__ __align__(16) u16 As[128 * 64];
  __shared__ __align__(16) u16 Bs[128 * 64];

  const int tid = threadIdx.x;
  const int lane = tid & 63;
  const int wave = tid >> 6;

  const int L = blockIdx.x;
  const int per_xcd = G >> 3;
  const int g = (L & 7) * per_xcd + (L >> 3);
  const int e = g >> nshift;
  const int wb = g & ((1 << nshift) - 1);
  const int mt = wb & 7;           // M = 1024 always -> 8 row tiles (fastest: share B)
  const int nt = wb >> 3;
  const int m0 = mt << 7, n0 = nt << 7;

  const u16* Aexp = A + (size_t)((e >> a_shift) * a_mul);
  const u16* Bexp = BT + (size_t)e * (size_t)N * (size_t)K;

  // staging: chunk c (of 16) = 1KB = 8 rows; lane l -> row c*8 + l/8, swizzled col group
  const int colsw = (((lane & 7) ^ ((lane >> 3) & 7)) << 3);
  const u16* aptr[4];
  const u16* bptr[4];
  u16* lA[4];
  u16* lB[4];
#pragma unroll
  for (int i = 0; i < 4; i++) {
    const int cch = wave * 4 + i;
    const int row = cch * 8 + (lane >> 3);
    aptr[i] = Aexp + (size_t)(m0 + row) * lda + colsw;
    bptr[i] = Bexp + (size_t)(n0 + row) * K + colsw;
    lA[i] = As + cch * 512;
    lB[i] = Bs + cch * 512;
  }

  floatx4 acc[4][4];
#pragma unroll
  for (int i = 0; i < 4; i++)
#pragma unroll
    for (int j = 0; j < 4; j++) acc[i][j] = (floatx4){0.f, 0.f, 0.f, 0.f};

  const int wm = (wave & 1) << 6;
  const int wn = (wave >> 1) << 6;
  const int r15 = lane & 15;
  const int quad = lane >> 4;

  int aoff[4], boff[4];
#pragma unroll
  for (int i = 0; i < 4; i++) {
    const int ra = wm + i * 16 + r15;
    aoff[i] = ra * 64 + ((quad ^ (ra & 7)) << 3);
    const int rb = wn + i * 16 + r15;
    boff[i] = rb * 64 + ((quad ^ (rb & 7)) << 3);
  }

  for (int k0 = 0; k0 < K; k0 += 64) {
    __syncthreads();
#pragma unroll
    for (int i = 0; i < 4; i++) GLOAD_LDS16(aptr[i] + k0, lA[i]);
#pragma unroll
    for (int i = 0; i < 4; i++) GLOAD_LDS16(bptr[i] + k0, lB[i]);
    __syncthreads();
#pragma unroll
    for (int s = 0; s < 2; s++) {
      short8 af[4], bfr[4];
#pragma unroll
      for (int i = 0; i < 4; i++) af[i] = *(const short8*)(As + (aoff[i] ^ (s << 5)));
#pragma unroll
      for (int j = 0; j < 4; j++) bfr[j] = *(const short8*)(Bs + (boff[j] ^ (s << 5)));
#pragma unroll
      for (int i = 0; i < 4; i++)
#pragma unroll
        for (int j = 0; j < 4; j++)
          acc[i][j] = __builtin_amdgcn_mfma_f32_16x16x32_bf16(af[i], bfr[j], acc[i][j], 0, 0, 0);
    }
  }

  const int ccol0 = n0 + wn + r15;
  const int crow0 = m0 + wm + quad * 4;
  float bv[4];
#pragma unroll
  for (int j = 0; j < 4; j++) bv[j] = bias[e * N + ccol0 + j * 16];

  if constexpr (RELU_BF16_OUT) {
    u16* Co = (u16*)Cout + (size_t)e * c_mul;
#pragma unroll
    for (int i = 0; i < 4; i++)
#pragma unroll
      for (int r = 0; r < 4; r++) {
        const size_t rowoff = (size_t)(crow0 + i * 16 + r) * ldc;
#pragma unroll
        for (int j = 0; j < 4; j++) {
          float v = acc[i][j][r] + bv[j];
          v = v > 0.f ? v : 0.f;
          Co[rowoff + ccol0 + j * 16] = f2bf(v);
        }
      }
  } else {
    float* Co = (float*)Cout + (size_t)e * c_mul;
#pragma unroll
    for (int i = 0; i < 4; i++)
#pragma unroll
      for (int r = 0; r < 4; r++) {
        const size_t rowoff = (size_t)(crow0 + i * 16 + r) * ldc;
#pragma unroll
        for (int j = 0; j < 4; j++) Co[rowoff + ccol0 + j * 16] = acc[i][j][r] + bv[j];
      }
  }
}

// ---------------- weighted sum: out[b][m][:] = sum_e wsm[b][m][e] * eo[b][e][:] -------
template <int M, bool BF16OUT>
__global__ __launch_bounds__(256) void wsum_kernel(
    const float* __restrict__ eo, const float* __restrict__ wsm,
    float* __restrict__ outf, u16* __restrict__ outb) {
  __shared__ float ws[2 * M * 18];
  const int t = threadIdx.x;
  const int b0 = blockIdx.x * 2;
  for (int i = t; i < 2 * M * 18; i += 256) ws[i] = wsm[(size_t)b0 * M * 18 + i];
  __syncthreads();
  const int lb = t >> 7;
  const int s = t & 127;
  const int b = b0 + lb;
  const float* eob = eo + (size_t)b * 9216 + s * 4;
  const float* wr = ws + lb * M * 18;

  float4 acc[M];
#pragma unroll
  for (int m = 0; m < M; m++) acc[m] = make_float4(0.f, 0.f, 0.f, 0.f);
#pragma unroll
  for (int e = 0; e < 18; e++) {
    const float4 v = *(const float4*)(eob + e * 512);
#pragma unroll
    for (int m = 0; m < M; m++) {
      const float w = wr[m * 18 + e];
      acc[m].x = fmaf(w, v.x, acc[m].x);
      acc[m].y = fmaf(w, v.y, acc[m].y);
      acc[m].z = fmaf(w, v.z, acc[m].z);
      acc[m].w = fmaf(w, v.w, acc[m].w);
    }
  }
  if constexpr (BF16OUT) {
    u16* ob = outb + (size_t)b * 4608 + s * 4;
#pragma unroll
    for (int m = 0; m < M; m++) {
      u32 lo = (u32)f2bf(acc[m].x) | ((u32)f2bf(acc[m].y) << 16);
      u32 hi = (u32)f2bf(acc[m].z) | ((u32)f2bf(acc[m].w) << 16);
      *(uint2*)(ob + m * 512) = make_uint2(lo, hi);
    }
  } else {
    float* ob = outf + (size_t)b * (M * 512) + s * 4;
#pragma unroll
    for (int m = 0; m < M; m++) *(float4*)(ob + m * 512) = acc[m];
  }
}

extern "C" void kernel_launch(void* const* d_in, const int* in_sizes, int n_in,
                              void* d_out, int out_size, void* d_ws, size_t ws_size,
                              hipStream_t stream) {
  const float* x0   = (const float*)d_in[0];
  const float* W1_0 = (const float*)d_in[1];
  const float* b1_0 = (const float*)d_in[2];
  const float* W2_0 = (const float*)d_in[3];
  const float* b2_0 = (const float*)d_in[4];
  const float* Wg_0 = (const float*)d_in[5];
  const float* bg_0 = (const float*)d_in[6];
  const float* W1_1 = (const float*)d_in[7];
  const float* b1_1 = (const float*)d_in[8];
  const float* W2_1 = (const float*)d_in[9];
  const float* b2_1 = (const float*)d_in[10];
  const float* Wg_1 = (const float*)d_in[11];
  const float* bg_1 = (const float*)d_in[12];
  const float* sewt = (const float*)d_in[13];
  const float* sews = (const float*)d_in[14];
  float* out = (float*)d_out;

  char* p = (char*)d_ws;
  auto take = [&](size_t n) { char* r = p; p += (n + 255) & ~(size_t)255; return r; };
  u16*   x0bf = (u16*)take(4718592ull * 2);     // [B][9][512] bf16
  u16*   W1T0 = (u16*)take(9437184ull * 2);     // [18][1024][512] bf16
  u16*   W2T0 = (u16*)take(9437184ull * 2);     // [18][512][1024] bf16
  u16*   W1T1 = (u16*)take(9437184ull * 2);
  u16*   W2T1 = (u16*)take(9437184ull * 2);
  u16*   WgT0 = (u16*)take(82944ull * 2);       // [9][18][512] bf16
  u16*   WgT1 = (u16*)take(73728ull * 2);       // [8][18][512] bf16
  u16*   hbf  = (u16*)take(18874368ull * 2);    // [B][18][1024] bf16
  float* eo   = (float*)take(9437184ull * 4);   // [B][18][512] fp32
  u16*   x1bf = (u16*)take(4718592ull * 2);     // [B][9][512] bf16
  float* wsm0 = (float*)take(165888ull * 4);    // [B][9][18] fp32
  float* wsm1 = (float*)take(147456ull * 4);    // [B][8][18] fp32

  dim3 blk(256);
  // 1) all weight transposes + x0 conversion, one dispatch
  prep_kernel<<<dim3(14436), blk, 0, stream>>>(W1_0, W2_0, W1_1, W2_1,
                                               W1T0, W2T0, W1T1, W2T1,
                                               Wg_0, Wg_1, WgT0, WgT1, x0, x0bf);
  // 2) layer0 GEMM1 + gating0 (both depend only on prep outputs)
  gemm_fused_kernel<true, 9, 0, true><<<dim3(1152 + 1152), blk, 0, stream>>>(
      x0bf, W1T0, b1_0, (void*)hbf, 4608, 1, 512, 18432, 1024, 1024, 512, 6, 1152,
      WgT0, bg_0, sewt, sews, wsm0);
  // 3) layer0 GEMM2
  gemm_fused_kernel<false, 9, 0, false><<<dim3(576), blk, 0, stream>>>(
      hbf, W2T0, b2_0, (void*)eo, 18432, 0, 1024, 9216, 512, 512, 1024, 5, 576,
      nullptr, nullptr, nullptr, nullptr, nullptr);
  // 4) layer0 combine -> x1 (bf16)
  wsum_kernel<9, true><<<dim3(512), blk, 0, stream>>>(eo, wsm0, nullptr, x1bf);
  // 5) layer1 GEMM1 + gating1 (both depend only on x1bf + prep outputs)
  gemm_fused_kernel<true, 8, 1, true><<<dim3(1152 + 1024), blk, 0, stream>>>(
      x1bf, W1T1, b1_1, (void*)hbf, 4608, 1, 512, 18432, 1024, 1024, 512, 6, 1152,
      WgT1, bg_1, sewt, sews, wsm1);
  // 6) layer1 GEMM2
  gemm_fused_kernel<false, 8, 1, false><<<dim3(576), blk, 0, stream>>>(
      hbf, W2T1, b2_1, (void*)eo, 18432, 0, 1024, 9216, 512, 512, 1024, 5, 576,
      nullptr, nullptr, nullptr, nullptr, nullptr);
  // 7) layer1 combine -> out (fp32)
  wsum_kernel<8, false><<<dim3(512), blk, 0, stream>>>(eo, wsm1, out, nullptr);
}